// Round 2
// baseline (1060.231 us; speedup 1.0000x reference)
//
#include <hip/hip_runtime.h>

#define N_POINTS   2000000
#define NUM_GRAPHS 16384
#define HID        40
#define SLOPE      0.01f
#define ROWP       260   // padded LDS row stride (floats) for xoT: 260%32=4 -> spreads banks, 1040B is 16B-aligned

__device__ __forceinline__ float lrelu(float v) { return v > 0.f ? v : SLOPE * v; }

// ---------------- Pass A: emb FFN + segment-sum xe[5] -> x_aggr [B,5] ----------------
// Weights read directly from global with literal indices -> uniform loads -> s_load/K$
__global__ __launch_bounds__(256) void k_emb_aggr(
    const float* __restrict__ x, const int* __restrict__ batch,
    const float* __restrict__ We1, const float* __restrict__ We2,
    float* __restrict__ x_aggr)
{
    int i = blockIdx.x * 256 + threadIdx.x;
    bool valid = i < N_POINTS;
    int ic = valid ? i : (N_POINTS - 1);
    float x0 = x[ic * 3 + 0], x1 = x[ic * 3 + 1], x2 = x[ic * 3 + 2];
    int b = valid ? batch[ic] : -1;

    float h[HID];
#pragma unroll
    for (int j = 0; j < HID; ++j)
        h[j] = lrelu(x0 * We1[j] + x1 * We1[HID + j] + x2 * We1[2 * HID + j]);

    float xe[5];
#pragma unroll
    for (int c = 0; c < 5; ++c) {
        float s = 0.f;
#pragma unroll
        for (int j = 0; j < HID; ++j) s += h[j] * We2[j * 5 + c];
        xe[c] = valid ? lrelu(s) : 0.f;
    }

    // wave segmented inclusive scan (batch sorted -> runs within wave); only 5 channels
    int lane = threadIdx.x & 63;
#pragma unroll
    for (int d = 1; d < 64; d <<= 1) {
        int bo = __shfl_up(b, d);
        bool ok = (lane >= d) && (bo == b);
#pragma unroll
        for (int c = 0; c < 5; ++c) {
            float vo = __shfl_up(xe[c], d);
            if (ok) xe[c] += vo;
        }
    }
    int bn = __shfl_down(b, 1);
    bool lastl = (lane == 63) || (bn != b);
    if (lastl && b >= 0) {
#pragma unroll
        for (int c = 0; c < 5; ++c) atomicAdd(&x_aggr[b * 5 + c], xe[c]);
    }
}

// ---------------- Pass B: per-graph global FFN + fold into W_out1 rows 5..8 ----------------
__global__ __launch_bounds__(256) void k_global(
    const float* __restrict__ x_aggr,
    const float* __restrict__ Wg1, const float* __restrict__ Wg2,
    const float* __restrict__ Wo1,          // full [9][40]
    float* __restrict__ g_contrib)
{
    int bg = blockIdx.x * 256 + threadIdx.x;
    if (bg >= NUM_GRAPHS) return;

    float a[5];
#pragma unroll
    for (int c = 0; c < 5; ++c) a[c] = x_aggr[bg * 5 + c];

    float h[HID];
#pragma unroll
    for (int j = 0; j < HID; ++j) {
        float s = 0.f;
#pragma unroll
        for (int c = 0; c < 5; ++c) s += a[c] * Wg1[c * HID + j];
        h[j] = lrelu(s);
    }
    float g[4];
#pragma unroll
    for (int c = 0; c < 4; ++c) {
        float s = 0.f;
#pragma unroll
        for (int j = 0; j < HID; ++j) s += h[j] * Wg2[j * 4 + c];
        g[c] = lrelu(s);
    }
#pragma unroll
    for (int j = 0; j < HID; ++j) {
        float s = 0.f;
#pragma unroll
        for (int c = 0; c < 4; ++c) s += g[c] * Wo1[(5 + c) * HID + j];
        g_contrib[bg * HID + j] = s;
    }
}

// ---------------- Pass C: recompute emb, out FFN, block-transpose segmented pooling ----------------
__global__ __launch_bounds__(256) void k_out_pool(
    const float* __restrict__ x, const int* __restrict__ batch,
    const float* __restrict__ We1, const float* __restrict__ We2,
    const float* __restrict__ Wo1, const float* __restrict__ Wo2,
    const float* __restrict__ g_contrib,
    float* __restrict__ pooled)
{
    __shared__ float xoT[32][ROWP];   // transposed xo: [channel][point-in-block]
    __shared__ int   sb[256];

    int tid = threadIdx.x;
    int i = blockIdx.x * 256 + tid;
    bool valid = i < N_POINTS;
    int ic = valid ? i : (N_POINTS - 1);
    float x0 = x[ic * 3 + 0], x1 = x[ic * 3 + 1], x2 = x[ic * 3 + 2];
    int b = valid ? batch[ic] : -1;
    sb[tid] = b;

    // emb recompute (cheaper than an 80MB HBM round-trip for xe)
    float h[HID];
#pragma unroll
    for (int j = 0; j < HID; ++j)
        h[j] = lrelu(x0 * We1[j] + x1 * We1[HID + j] + x2 * We1[2 * HID + j]);

    float xe[5];
#pragma unroll
    for (int c = 0; c < 5; ++c) {
        float s = 0.f;
#pragma unroll
        for (int j = 0; j < HID; ++j) s += h[j] * We2[j * 5 + c];
        xe[c] = lrelu(s);
    }

    // h1 = lrelu(xe @ Wo1[0:5] + g_contrib[b]); gc gathered as float4 (L2-resident, 2.6MB)
    const float4* gc4 = (const float4*)(g_contrib + (size_t)(valid ? b : 0) * HID);
    float h1[HID];
#pragma unroll
    for (int jj = 0; jj < HID / 4; ++jj) {
        float4 g = gc4[jj];
        float gg[4] = {g.x, g.y, g.z, g.w};
#pragma unroll
        for (int k = 0; k < 4; ++k) {
            int j = jj * 4 + k;
            float s = gg[k];
#pragma unroll
            for (int c = 0; c < 5; ++c) s += xe[c] * Wo1[c * HID + j];
            h1[j] = lrelu(s);
        }
    }

    // xo = lrelu(h1 @ Wo2), written transposed to LDS (conflict-free: lanes hit consecutive banks)
#pragma unroll
    for (int c = 0; c < 32; ++c) {
        float s = 0.f;
#pragma unroll
        for (int j = 0; j < HID; ++j) s += h1[j] * Wo2[j * 32 + c];
        xoT[c][tid] = valid ? lrelu(s) : 0.f;
    }
    __syncthreads();

    // each thread reduces one (channel, 32-point chunk) with a running segmented sum.
    // fully general w.r.t. segment boundaries; cross-block segments compose via atomicAdd.
    int ch = tid & 31, chunk = tid >> 5;
    const float4* row4 = (const float4*)&xoT[ch][chunk * 32];
    const int4*   b4   = (const int4*)&sb[chunk * 32];
    float acc = 0.f;
    int cur = sb[chunk * 32];
#pragma unroll
    for (int g = 0; g < 8; ++g) {
        float4 v4 = row4[g];
        int4   n4 = b4[g];
        float vv[4] = {v4.x, v4.y, v4.z, v4.w};
        int   nn[4] = {n4.x, n4.y, n4.z, n4.w};
#pragma unroll
        for (int k = 0; k < 4; ++k) {
            if (nn[k] != cur) {
                if (cur >= 0) atomicAdd(&pooled[cur * 32 + ch], acc);
                cur = nn[k];
                acc = vv[k];
            } else {
                acc += vv[k];
            }
        }
    }
    if (cur >= 0) atomicAdd(&pooled[cur * 32 + ch], acc);
}

// ---------------- Pass D: disc head per graph ----------------
__global__ __launch_bounds__(256) void k_disc(
    const float* __restrict__ pooled,
    const float* __restrict__ Wd1, const float* __restrict__ Wd2,
    float* __restrict__ out)
{
    int bg = blockIdx.x * 256 + threadIdx.x;
    if (bg >= NUM_GRAPHS) return;

    float p[32];
#pragma unroll
    for (int c = 0; c < 32; ++c) p[c] = pooled[bg * 32 + c];

    float acc = 0.f;
#pragma unroll
    for (int j = 0; j < HID; ++j) {
        float s = 0.f;
#pragma unroll
        for (int c = 0; c < 32; ++c) s += p[c] * Wd1[c * HID + j];
        acc += lrelu(s) * Wd2[j];
    }
    out[bg] = acc;
}

extern "C" void kernel_launch(void* const* d_in, const int* in_sizes, int n_in,
                              void* d_out, int out_size, void* d_ws, size_t ws_size,
                              hipStream_t stream) {
    const float* x     = (const float*)d_in[0];
    const int*   batch = (const int*)  d_in[1];
    const float* We1   = (const float*)d_in[2];
    const float* We2   = (const float*)d_in[3];
    const float* Wg1   = (const float*)d_in[4];
    const float* Wg2   = (const float*)d_in[5];
    const float* Wo1   = (const float*)d_in[6];
    const float* Wo2   = (const float*)d_in[7];
    const float* Wd1   = (const float*)d_in[8];
    const float* Wd2   = (const float*)d_in[9];
    float* out = (float*)d_out;

    // workspace layout: [x_aggr B*5][pooled B*32][g_contrib B*40]
    float* x_aggr    = (float*)d_ws;
    float* pooled    = x_aggr + NUM_GRAPHS * 5;
    float* g_contrib = pooled + NUM_GRAPHS * 32;

    // zero the atomic accumulators (ws is poisoned to 0xAA before every launch)
    hipMemsetAsync(d_ws, 0, (size_t)NUM_GRAPHS * (5 + 32) * sizeof(float), stream);

    int nblk = (N_POINTS + 255) / 256;
    int gblk = (NUM_GRAPHS + 255) / 256;
    k_emb_aggr<<<nblk, 256, 0, stream>>>(x, batch, We1, We2, x_aggr);
    k_global <<<gblk, 256, 0, stream>>>(x_aggr, Wg1, Wg2, Wo1, g_contrib);
    k_out_pool<<<nblk, 256, 0, stream>>>(x, batch, We1, We2, Wo1, Wo2, g_contrib, pooled);
    k_disc   <<<gblk, 256, 0, stream>>>(pooled, Wd1, Wd2, out);
}

// Round 3
// 326.615 us; speedup vs baseline: 3.2461x; 3.2461x over previous
//
#include <hip/hip_runtime.h>

#define N_POINTS   2000000
#define NUM_GRAPHS 16384
#define HID        40
#define SLOPE      0.01f
#define XO_STRIDE  516   // dword stride: %32==4 -> 2-way max conflict (free), 16B aligned
#define SB_STRIDE  36    // dword stride: %32==4, 16B aligned

__device__ __forceinline__ float lrelu(float v) { return v > 0.f ? v : SLOPE * v; }

// ---------------- Pass A: emb FFN + segment-sum xe[5] -> x_aggr; 512 pts/block ----------------
__global__ __launch_bounds__(256) void k_emb_aggr(
    const float* __restrict__ x, const int* __restrict__ batch,
    const float* __restrict__ We1, const float* __restrict__ We2,
    float* __restrict__ x_aggr)
{
    __shared__ float sWe1[3 * HID];    // [3][40] as-is (j contiguous)
    __shared__ float sWe2T[5 * HID];   // transposed: [c][j]
    int tid = threadIdx.x;
    for (int k = tid; k < 3 * HID; k += 256) sWe1[k] = We1[k];
    for (int k = tid; k < 5 * HID; k += 256) sWe2T[k] = We2[(k % HID) * 5 + k / HID];
    __syncthreads();

    int p0 = blockIdx.x * 512 + tid, p1 = p0 + 256;
    bool v0 = p0 < N_POINTS, v1 = p1 < N_POINTS;
    int i0 = v0 ? p0 : (N_POINTS - 1), i1 = v1 ? p1 : (N_POINTS - 1);
    float a0 = x[i0 * 3 + 0], a1 = x[i0 * 3 + 1], a2 = x[i0 * 3 + 2];
    float b0x = x[i1 * 3 + 0], b1x = x[i1 * 3 + 1], b2x = x[i1 * 3 + 2];
    int b0 = v0 ? batch[i0] : -1;
    int b1 = v1 ? batch[i1] : -1;

    float h0[HID], h1[HID];
    const float4* W1r = (const float4*)sWe1;
#pragma unroll
    for (int j4 = 0; j4 < HID / 4; ++j4) {
        float4 wa = W1r[j4], wb = W1r[10 + j4], wc = W1r[20 + j4];
        float wav[4] = {wa.x, wa.y, wa.z, wa.w};
        float wbv[4] = {wb.x, wb.y, wb.z, wb.w};
        float wcv[4] = {wc.x, wc.y, wc.z, wc.w};
#pragma unroll
        for (int k = 0; k < 4; ++k) {
            int j = j4 * 4 + k;
            h0[j] = lrelu(a0 * wav[k] + a1 * wbv[k] + a2 * wcv[k]);
            h1[j] = lrelu(b0x * wav[k] + b1x * wbv[k] + b2x * wcv[k]);
        }
    }

    float xe0[5], xe1[5];
#pragma unroll
    for (int c = 0; c < 5; ++c) {
        const float4* wr = (const float4*)&sWe2T[c * HID];
        float s0 = 0.f, s1 = 0.f;
#pragma unroll
        for (int j4 = 0; j4 < HID / 4; ++j4) {
            float4 w = wr[j4];
            float wv[4] = {w.x, w.y, w.z, w.w};
#pragma unroll
            for (int k = 0; k < 4; ++k) {
                s0 += h0[j4 * 4 + k] * wv[k];
                s1 += h1[j4 * 4 + k] * wv[k];
            }
        }
        xe0[c] = v0 ? lrelu(s0) : 0.f;
        xe1[c] = v1 ? lrelu(s1) : 0.f;
    }

    int lane = tid & 63;
    // segmented scan, point-set 0
    {
        int b = b0;
#pragma unroll
        for (int s6 = 0; s6 < 6; ++s6) {
            int d = 1 << s6;
            int bo = __shfl_up(b, d);
            bool ok = (lane >= d) && (bo == b);
#pragma unroll
            for (int c = 0; c < 5; ++c) {
                float vo = __shfl_up(xe0[c], d);
                if (ok) xe0[c] += vo;
            }
        }
        int bn = __shfl_down(b, 1);
        bool last = (lane == 63) || (bn != b);
        if (last && b >= 0) {
#pragma unroll
            for (int c = 0; c < 5; ++c) atomicAdd(&x_aggr[b * 5 + c], xe0[c]);
        }
    }
    // segmented scan, point-set 1
    {
        int b = b1;
#pragma unroll
        for (int s6 = 0; s6 < 6; ++s6) {
            int d = 1 << s6;
            int bo = __shfl_up(b, d);
            bool ok = (lane >= d) && (bo == b);
#pragma unroll
            for (int c = 0; c < 5; ++c) {
                float vo = __shfl_up(xe1[c], d);
                if (ok) xe1[c] += vo;
            }
        }
        int bn = __shfl_down(b, 1);
        bool last = (lane == 63) || (bn != b);
        if (last && b >= 0) {
#pragma unroll
            for (int c = 0; c < 5; ++c) atomicAdd(&x_aggr[b * 5 + c], xe1[c]);
        }
    }
}

// ---------------- Pass B: per-graph global FFN + fold into W_out1 rows 5..8 ----------------
__global__ __launch_bounds__(256) void k_global(
    const float* __restrict__ x_aggr,
    const float* __restrict__ Wg1, const float* __restrict__ Wg2,
    const float* __restrict__ Wo1,
    float* __restrict__ g_contrib)
{
    __shared__ float sWg1[5 * HID];
    __shared__ float sWg2[HID * 4];
    __shared__ float sWo1g[4 * HID];
    for (int k = threadIdx.x; k < 5 * HID; k += 256) sWg1[k] = Wg1[k];
    for (int k = threadIdx.x; k < HID * 4; k += 256) sWg2[k] = Wg2[k];
    for (int k = threadIdx.x; k < 4 * HID; k += 256) sWo1g[k] = Wo1[5 * HID + k];
    __syncthreads();

    int bg = blockIdx.x * 256 + threadIdx.x;
    if (bg >= NUM_GRAPHS) return;

    float a[5];
#pragma unroll
    for (int c = 0; c < 5; ++c) a[c] = x_aggr[bg * 5 + c];

    float h[HID];
#pragma unroll
    for (int j = 0; j < HID; ++j) {
        float s = 0.f;
#pragma unroll
        for (int c = 0; c < 5; ++c) s += a[c] * sWg1[c * HID + j];
        h[j] = lrelu(s);
    }
    float g[4];
#pragma unroll
    for (int c = 0; c < 4; ++c) {
        float s = 0.f;
#pragma unroll
        for (int j = 0; j < HID; ++j) s += h[j] * sWg2[j * 4 + c];
        g[c] = lrelu(s);
    }
#pragma unroll
    for (int j = 0; j < HID; ++j) {
        float s = 0.f;
#pragma unroll
        for (int c = 0; c < 4; ++c) s += g[c] * sWo1g[c * HID + j];
        g_contrib[bg * HID + j] = s;
    }
}

// ---------------- Pass C: recompute emb, out FFN, transpose-pool; 512 pts/block ----------------
__global__ __launch_bounds__(256) void k_out_pool(
    const float* __restrict__ x, const int* __restrict__ batch,
    const float* __restrict__ We1, const float* __restrict__ We2,
    const float* __restrict__ Wo1, const float* __restrict__ Wo2,
    const float* __restrict__ g_contrib,
    float* __restrict__ pooled)
{
    __shared__ float sWe1[3 * HID];
    __shared__ float sWe2T[5 * HID];       // [c][j]
    __shared__ float sWo1[5 * HID];        // rows 0..4, already [c][j]
    __shared__ float sWo2T[32 * HID];      // [c][j]
    __shared__ float xoT[16 * XO_STRIDE];  // 16 channels x 512 pts (padded)
    __shared__ int   sb2[16 * SB_STRIDE];  // 16 chunks x 32 batch ids (padded)

    int tid = threadIdx.x;
    for (int k = tid; k < 3 * HID; k += 256) sWe1[k] = We1[k];
    for (int k = tid; k < 5 * HID; k += 256) sWe2T[k] = We2[(k % HID) * 5 + k / HID];
    for (int k = tid; k < 5 * HID; k += 256) sWo1[k] = Wo1[k];
    for (int k = tid; k < 32 * HID; k += 256) sWo2T[k] = Wo2[(k % HID) * 32 + k / HID];

    int p0 = blockIdx.x * 512 + tid, p1 = p0 + 256;
    bool v0 = p0 < N_POINTS, v1 = p1 < N_POINTS;
    int i0 = v0 ? p0 : (N_POINTS - 1), i1 = v1 ? p1 : (N_POINTS - 1);
    float a0 = x[i0 * 3 + 0], a1 = x[i0 * 3 + 1], a2 = x[i0 * 3 + 2];
    float b0x = x[i1 * 3 + 0], b1x = x[i1 * 3 + 1], b2x = x[i1 * 3 + 2];
    int b0 = v0 ? batch[i0] : -1;
    int b1 = v1 ? batch[i1] : -1;
    // sb2[chunk][col]: point q=tid -> chunk tid>>5, col tid&31; point q=tid+256 -> chunk 8+(tid>>5)
    sb2[(tid >> 5) * SB_STRIDE + (tid & 31)] = b0;
    sb2[(8 + (tid >> 5)) * SB_STRIDE + (tid & 31)] = b1;
    __syncthreads();

    // emb recompute
    float h0[HID], h1[HID];
    const float4* W1r = (const float4*)sWe1;
#pragma unroll
    for (int j4 = 0; j4 < HID / 4; ++j4) {
        float4 wa = W1r[j4], wb = W1r[10 + j4], wc = W1r[20 + j4];
        float wav[4] = {wa.x, wa.y, wa.z, wa.w};
        float wbv[4] = {wb.x, wb.y, wb.z, wb.w};
        float wcv[4] = {wc.x, wc.y, wc.z, wc.w};
#pragma unroll
        for (int k = 0; k < 4; ++k) {
            int j = j4 * 4 + k;
            h0[j] = lrelu(a0 * wav[k] + a1 * wbv[k] + a2 * wcv[k]);
            h1[j] = lrelu(b0x * wav[k] + b1x * wbv[k] + b2x * wcv[k]);
        }
    }
    float xe0[5], xe1[5];
#pragma unroll
    for (int c = 0; c < 5; ++c) {
        const float4* wr = (const float4*)&sWe2T[c * HID];
        float s0 = 0.f, s1 = 0.f;
#pragma unroll
        for (int j4 = 0; j4 < HID / 4; ++j4) {
            float4 w = wr[j4];
            float wv[4] = {w.x, w.y, w.z, w.w};
#pragma unroll
            for (int k = 0; k < 4; ++k) {
                s0 += h0[j4 * 4 + k] * wv[k];
                s1 += h1[j4 * 4 + k] * wv[k];
            }
        }
        xe0[c] = lrelu(s0);
        xe1[c] = lrelu(s1);
    }

    // h1-layer: lrelu(xe @ Wo1[0:5] + g_contrib[b]) -> reuse h0/h1 storage
    const float4* gc0 = (const float4*)(g_contrib + (size_t)(v0 ? b0 : 0) * HID);
    const float4* gc1 = (const float4*)(g_contrib + (size_t)(v1 ? b1 : 0) * HID);
#pragma unroll
    for (int j4 = 0; j4 < HID / 4; ++j4) {
        float4 g0 = gc0[j4], g1 = gc1[j4];
        float s0v[4] = {g0.x, g0.y, g0.z, g0.w};
        float s1v[4] = {g1.x, g1.y, g1.z, g1.w};
#pragma unroll
        for (int c = 0; c < 5; ++c) {
            float4 w = ((const float4*)&sWo1[c * HID])[j4];
            float wv[4] = {w.x, w.y, w.z, w.w};
#pragma unroll
            for (int k = 0; k < 4; ++k) {
                s0v[k] += xe0[c] * wv[k];
                s1v[k] += xe1[c] * wv[k];
            }
        }
#pragma unroll
        for (int k = 0; k < 4; ++k) {
            h0[j4 * 4 + k] = lrelu(s0v[k]);
            h1[j4 * 4 + k] = lrelu(s1v[k]);
        }
    }

    // xo = lrelu(h @ Wo2): two 16-channel passes, each staged+reduced through LDS
#pragma unroll 1
    for (int half = 0; half < 2; ++half) {
#pragma unroll
        for (int cc = 0; cc < 16; ++cc) {
            int c = half * 16 + cc;
            const float4* wr = (const float4*)&sWo2T[c * HID];
            float s0 = 0.f, s1 = 0.f;
#pragma unroll
            for (int j4 = 0; j4 < HID / 4; ++j4) {
                float4 w = wr[j4];
                float wv[4] = {w.x, w.y, w.z, w.w};
#pragma unroll
                for (int k = 0; k < 4; ++k) {
                    s0 += h0[j4 * 4 + k] * wv[k];
                    s1 += h1[j4 * 4 + k] * wv[k];
                }
            }
            xoT[cc * XO_STRIDE + tid]       = v0 ? lrelu(s0) : 0.f;
            xoT[cc * XO_STRIDE + 256 + tid] = v1 ? lrelu(s1) : 0.f;
        }
        __syncthreads();

        // reduce: thread owns (channel ch, 32-pt chunk); running segmented sum
        int ch = tid & 15, chunk = tid >> 4;
        float acc = 0.f;
        int cur = sb2[chunk * SB_STRIDE];
#pragma unroll
        for (int g = 0; g < 8; ++g) {
            float4 v4 = *(const float4*)&xoT[ch * XO_STRIDE + chunk * 32 + g * 4];
            int4   n4 = *(const int4*)&sb2[chunk * SB_STRIDE + g * 4];
            float vv[4] = {v4.x, v4.y, v4.z, v4.w};
            int   nn[4] = {n4.x, n4.y, n4.z, n4.w};
#pragma unroll
            for (int k = 0; k < 4; ++k) {
                if (nn[k] != cur) {
                    if (cur >= 0) atomicAdd(&pooled[cur * 32 + half * 16 + ch], acc);
                    cur = nn[k];
                    acc = vv[k];
                } else {
                    acc += vv[k];
                }
            }
        }
        if (cur >= 0) atomicAdd(&pooled[cur * 32 + half * 16 + ch], acc);
        __syncthreads();
    }
}

// ---------------- Pass D: disc head per graph ----------------
__global__ __launch_bounds__(256) void k_disc(
    const float* __restrict__ pooled,
    const float* __restrict__ Wd1, const float* __restrict__ Wd2,
    float* __restrict__ out)
{
    __shared__ float sWd1T[HID * 32];  // [j][c] transposed so dot over c is contiguous
    __shared__ float sWd2[HID];
    for (int k = threadIdx.x; k < 32 * HID; k += 256) sWd1T[k] = Wd1[(k % 32) * HID + k / 32];
    for (int k = threadIdx.x; k < HID; k += 256) sWd2[k] = Wd2[k];
    __syncthreads();

    int bg = blockIdx.x * 256 + threadIdx.x;
    if (bg >= NUM_GRAPHS) return;

    float p[32];
    const float4* pp = (const float4*)(pooled + (size_t)bg * 32);
#pragma unroll
    for (int c4 = 0; c4 < 8; ++c4) {
        float4 v = pp[c4];
        p[c4 * 4 + 0] = v.x; p[c4 * 4 + 1] = v.y; p[c4 * 4 + 2] = v.z; p[c4 * 4 + 3] = v.w;
    }

    float acc = 0.f;
#pragma unroll
    for (int j = 0; j < HID; ++j) {
        const float4* wr = (const float4*)&sWd1T[j * 32];
        float s = 0.f;
#pragma unroll
        for (int c4 = 0; c4 < 8; ++c4) {
            float4 w = wr[c4];
            s += p[c4 * 4 + 0] * w.x + p[c4 * 4 + 1] * w.y + p[c4 * 4 + 2] * w.z + p[c4 * 4 + 3] * w.w;
        }
        acc += lrelu(s) * sWd2[j];
    }
    out[bg] = acc;
}

extern "C" void kernel_launch(void* const* d_in, const int* in_sizes, int n_in,
                              void* d_out, int out_size, void* d_ws, size_t ws_size,
                              hipStream_t stream) {
    const float* x     = (const float*)d_in[0];
    const int*   batch = (const int*)  d_in[1];
    const float* We1   = (const float*)d_in[2];
    const float* We2   = (const float*)d_in[3];
    const float* Wg1   = (const float*)d_in[4];
    const float* Wg2   = (const float*)d_in[5];
    const float* Wo1   = (const float*)d_in[6];
    const float* Wo2   = (const float*)d_in[7];
    const float* Wd1   = (const float*)d_in[8];
    const float* Wd2   = (const float*)d_in[9];
    float* out = (float*)d_out;

    float* x_aggr    = (float*)d_ws;
    float* pooled    = x_aggr + NUM_GRAPHS * 5;
    float* g_contrib = pooled + NUM_GRAPHS * 32;

    hipMemsetAsync(d_ws, 0, (size_t)NUM_GRAPHS * (5 + 32) * sizeof(float), stream);

    int nblk = (N_POINTS + 511) / 512;
    int gblk = (NUM_GRAPHS + 255) / 256;
    k_emb_aggr<<<nblk, 256, 0, stream>>>(x, batch, We1, We2, x_aggr);
    k_global <<<gblk, 256, 0, stream>>>(x_aggr, Wg1, Wg2, Wo1, g_contrib);
    k_out_pool<<<nblk, 256, 0, stream>>>(x, batch, We1, We2, Wo1, Wo2, g_contrib, pooled);
    k_disc   <<<gblk, 256, 0, stream>>>(pooled, Wd1, Wd2, out);
}

// Round 4
// 218.667 us; speedup vs baseline: 4.8486x; 1.4937x over previous
//
#include <hip/hip_runtime.h>
#include <hip/hip_bf16.h>

#define N_POINTS   2000000
#define NUM_GRAPHS 16384
#define HID        40
#define SLOPE      0.01f
#define TILE       256
#define NTILES     ((N_POINTS + TILE - 1) / TILE)   // 7813
#define AROW       20      // dwords per A-staging row: 5 cells x 16B; (5*tid+c)%8 covers all 8 bank-spans
#define XOS        260     // dwords per xoT channel row (%32==4, 16B aligned)

typedef __attribute__((ext_vector_type(8))) short short8;
typedef __attribute__((ext_vector_type(4))) float fx4;

__device__ __forceinline__ float lrelu(float v) { return v > 0.f ? v : SLOPE * v; }

// ---------------- Pass A: emb FFN + transpose-reduce segment-sum xe[5] -> x_aggr ----------------
__global__ __launch_bounds__(256) void k_emb_aggr(
    const float* __restrict__ x, const int* __restrict__ batch,
    const float* __restrict__ We1, const float* __restrict__ We2,
    float* __restrict__ x_aggr)
{
    __shared__ float sWe1[3 * HID];
    __shared__ float sWe2T[5 * HID];           // [c][j]
    __shared__ __align__(16) float xeT[5 * XOS];
    __shared__ __align__(16) int   sb[TILE];

    int tid = threadIdx.x;
    for (int k = tid; k < 3 * HID; k += 256) sWe1[k] = We1[k];
    for (int k = tid; k < 5 * HID; k += 256) sWe2T[k] = We2[(k % HID) * 5 + k / HID];
    __syncthreads();

    for (int t = blockIdx.x; t < NTILES; t += gridDim.x) {
        int i = t * TILE + tid;
        bool v = i < N_POINTS;
        int ic = v ? i : (N_POINTS - 1);
        float x0 = x[ic * 3 + 0], x1 = x[ic * 3 + 1], x2 = x[ic * 3 + 2];
        int b = v ? batch[ic] : -1;
        sb[tid] = b;

        float h[HID];
        const float4* W1r = (const float4*)sWe1;
#pragma unroll
        for (int j4 = 0; j4 < HID / 4; ++j4) {
            float4 wa = W1r[j4], wb = W1r[10 + j4], wc = W1r[20 + j4];
            float wav[4] = {wa.x, wa.y, wa.z, wa.w};
            float wbv[4] = {wb.x, wb.y, wb.z, wb.w};
            float wcv[4] = {wc.x, wc.y, wc.z, wc.w};
#pragma unroll
            for (int k = 0; k < 4; ++k)
                h[j4 * 4 + k] = lrelu(x0 * wav[k] + x1 * wbv[k] + x2 * wcv[k]);
        }
#pragma unroll
        for (int c = 0; c < 5; ++c) {
            const float4* wr = (const float4*)&sWe2T[c * HID];
            float s = 0.f;
#pragma unroll
            for (int j4 = 0; j4 < HID / 4; ++j4) {
                float4 w = wr[j4];
                s += h[j4 * 4 + 0] * w.x + h[j4 * 4 + 1] * w.y + h[j4 * 4 + 2] * w.z + h[j4 * 4 + 3] * w.w;
            }
            xeT[c * XOS + tid] = lrelu(s);   // conflict-free: consecutive lanes, consecutive banks
        }
        __syncthreads();

        // 40 threads reduce: ch = tid>>3 (0..4), chunk = tid&7 (32-pt chunks)
        if (tid < 40) {
            int ch = tid >> 3, chunk = tid & 7;
            float acc = 0.f;
            int cur = sb[chunk * 32];
#pragma unroll
            for (int g = 0; g < 8; ++g) {
                float4 v4 = *(const float4*)&xeT[ch * XOS + chunk * 32 + g * 4];
                int4   n4 = *(const int4*)&sb[chunk * 32 + g * 4];
                float vv[4] = {v4.x, v4.y, v4.z, v4.w};
                int   nn[4] = {n4.x, n4.y, n4.z, n4.w};
#pragma unroll
                for (int k = 0; k < 4; ++k) {
                    if (nn[k] != cur) {
                        if (cur >= 0) atomicAdd(&x_aggr[cur * 5 + ch], acc);
                        cur = nn[k];
                        acc = vv[k];
                    } else {
                        acc += vv[k];
                    }
                }
            }
            if (cur >= 0) atomicAdd(&x_aggr[cur * 5 + ch], acc);
        }
        __syncthreads();
    }
}

// ---------------- Pass B: per-graph global FFN + fold into W_out1 rows 5..8 ----------------
__global__ __launch_bounds__(256) void k_global(
    const float* __restrict__ x_aggr,
    const float* __restrict__ Wg1, const float* __restrict__ Wg2,
    const float* __restrict__ Wo1,
    float* __restrict__ g_contrib)
{
    __shared__ float sWg1[5 * HID];
    __shared__ float sWg2[HID * 4];
    __shared__ float sWo1g[4 * HID];
    for (int k = threadIdx.x; k < 5 * HID; k += 256) sWg1[k] = Wg1[k];
    for (int k = threadIdx.x; k < HID * 4; k += 256) sWg2[k] = Wg2[k];
    for (int k = threadIdx.x; k < 4 * HID; k += 256) sWo1g[k] = Wo1[5 * HID + k];
    __syncthreads();

    int bg = blockIdx.x * 256 + threadIdx.x;
    if (bg >= NUM_GRAPHS) return;

    float a[5];
#pragma unroll
    for (int c = 0; c < 5; ++c) a[c] = x_aggr[bg * 5 + c];

    float h[HID];
#pragma unroll
    for (int j = 0; j < HID; ++j) {
        float s = 0.f;
#pragma unroll
        for (int c = 0; c < 5; ++c) s += a[c] * sWg1[c * HID + j];
        h[j] = lrelu(s);
    }
    float g[4];
#pragma unroll
    for (int c = 0; c < 4; ++c) {
        float s = 0.f;
#pragma unroll
        for (int j = 0; j < HID; ++j) s += h[j] * sWg2[j * 4 + c];
        g[c] = lrelu(s);
    }
#pragma unroll
    for (int j = 0; j < HID; ++j) {
        float s = 0.f;
#pragma unroll
        for (int c = 0; c < 4; ++c) s += g[c] * sWo1g[c * HID + j];
        g_contrib[bg * HID + j] = s;
    }
}

// ---------------- Pass C: h1 on VALU, 40x32 layer on bf16 MFMA, transpose-reduce pool ----------------
__global__ __launch_bounds__(256, 4) void k_out_pool(
    const float* __restrict__ x, const int* __restrict__ batch,
    const float* __restrict__ We1, const float* __restrict__ We2,
    const float* __restrict__ Wo1, const float* __restrict__ Wo2,
    const float* __restrict__ g_contrib,
    float* __restrict__ pooled)
{
    // Aliased region: A-staging (256 rows x 20 dwords = 20480 B) then xoT (32 x 260 x 4 = 33280 B).
    __shared__ __align__(16) unsigned int uLds[32 * XOS];
    __shared__ __align__(16) int sb[TILE];
    __shared__ float sWe1[3 * HID];
    __shared__ float sWe2T[5 * HID];
    __shared__ float sWo1[5 * HID];

    int tid = threadIdx.x;
    for (int k = tid; k < 3 * HID; k += 256) sWe1[k] = We1[k];
    for (int k = tid; k < 5 * HID; k += 256) sWe2T[k] = We2[(k % HID) * 5 + k / HID];
    for (int k = tid; k < 5 * HID; k += 256) sWo1[k] = Wo1[k];

    int lane = tid & 63;
    int l16 = lane & 15, quad = lane >> 4;

    // B fragments (Wo2 -> bf16), built once. B[k][n]: lane l16 = n, k = ks*32 + quad*8 + j.
    short8 bfrag[2][2];
#pragma unroll
    for (int nt = 0; nt < 2; ++nt) {
#pragma unroll
        for (int ks = 0; ks < 2; ++ks) {
#pragma unroll
            for (int j = 0; j < 8; ++j) {
                int kk = ks * 32 + quad * 8 + j;
                float w = (kk < HID) ? Wo2[kk * 32 + nt * 16 + l16] : 0.f;
                __hip_bfloat16 hb = __float2bfloat16(w);
                bfrag[nt][ks][j] = *(short*)&hb;
            }
        }
    }
    short8 zfrag = {0, 0, 0, 0, 0, 0, 0, 0};
    __syncthreads();

    for (int t = blockIdx.x; t < NTILES; t += gridDim.x) {
        int i = t * TILE + tid;
        bool v = i < N_POINTS;
        int ic = v ? i : (N_POINTS - 1);
        float x0 = x[ic * 3 + 0], x1 = x[ic * 3 + 1], x2 = x[ic * 3 + 2];
        int b = v ? batch[ic] : -1;
        sb[tid] = b;

        // emb recompute
        float h[HID];
        const float4* W1r = (const float4*)sWe1;
#pragma unroll
        for (int j4 = 0; j4 < HID / 4; ++j4) {
            float4 wa = W1r[j4], wb = W1r[10 + j4], wc = W1r[20 + j4];
            float wav[4] = {wa.x, wa.y, wa.z, wa.w};
            float wbv[4] = {wb.x, wb.y, wb.z, wb.w};
            float wcv[4] = {wc.x, wc.y, wc.z, wc.w};
#pragma unroll
            for (int k = 0; k < 4; ++k)
                h[j4 * 4 + k] = lrelu(x0 * wav[k] + x1 * wbv[k] + x2 * wcv[k]);
        }
        float xe[5];
#pragma unroll
        for (int c = 0; c < 5; ++c) {
            const float4* wr = (const float4*)&sWe2T[c * HID];
            float s = 0.f;
#pragma unroll
            for (int j4 = 0; j4 < HID / 4; ++j4) {
                float4 w = wr[j4];
                s += h[j4 * 4 + 0] * w.x + h[j4 * 4 + 1] * w.y + h[j4 * 4 + 2] * w.z + h[j4 * 4 + 3] * w.w;
            }
            xe[c] = lrelu(s);
        }

        // h1 = lrelu(xe @ Wo1[0:5] + g_contrib[b]) (fp32)
        const float4* gc4 = (const float4*)(g_contrib + (size_t)(v ? b : 0) * HID);
        float h1v[HID];
#pragma unroll
        for (int j4 = 0; j4 < HID / 4; ++j4) {
            float4 g = gc4[j4];
            float sv[4] = {g.x, g.y, g.z, g.w};
#pragma unroll
            for (int c = 0; c < 5; ++c) {
                float4 w = ((const float4*)&sWo1[c * HID])[j4];
                float wv[4] = {w.x, w.y, w.z, w.w};
#pragma unroll
                for (int k = 0; k < 4; ++k) sv[k] += xe[c] * wv[k];
            }
#pragma unroll
            for (int k = 0; k < 4; ++k) h1v[j4 * 4 + k] = lrelu(sv[k]);
        }

        // pack h1 -> bf16, stage A row (wave-private rows: wave w stages rows w*64..w*64+63
        // and reads rows mt*16+l16 with mt in [4w,4w+4) -> same range; no barrier needed)
        unsigned int* row = &uLds[tid * AROW];
#pragma unroll
        for (int c = 0; c < 5; ++c) {
            __hip_bfloat162 p0 = __float22bfloat162_rn(make_float2(h1v[8 * c + 0], h1v[8 * c + 1]));
            __hip_bfloat162 p1 = __float22bfloat162_rn(make_float2(h1v[8 * c + 2], h1v[8 * c + 3]));
            __hip_bfloat162 p2 = __float22bfloat162_rn(make_float2(h1v[8 * c + 4], h1v[8 * c + 5]));
            __hip_bfloat162 p3 = __float22bfloat162_rn(make_float2(h1v[8 * c + 6], h1v[8 * c + 7]));
            uint4 u;
            u.x = *(unsigned int*)&p0; u.y = *(unsigned int*)&p1;
            u.z = *(unsigned int*)&p2; u.w = *(unsigned int*)&p3;
            *(uint4*)(row + c * 4) = u;
        }

        // MFMA: wave owns mtiles 4w..4w+3; 2 ntiles; K = 32 + 8 (second frag zero for quad>0)
        fx4 xov[4][2];
#pragma unroll
        for (int m = 0; m < 4; ++m) {
            int mt = (tid >> 6) * 4 + m;
            const unsigned int* arow = &uLds[(mt * 16 + l16) * AROW];
            short8 a0 = *(const short8*)(arow + quad * 4);
            short8 a1 = (quad == 0) ? *(const short8*)(arow + 16) : zfrag;
#pragma unroll
            for (int nt = 0; nt < 2; ++nt) {
                fx4 acc = {0.f, 0.f, 0.f, 0.f};
                acc = __builtin_amdgcn_mfma_f32_16x16x32_bf16(a0, bfrag[nt][0], acc, 0, 0, 0);
                acc = __builtin_amdgcn_mfma_f32_16x16x32_bf16(a1, bfrag[nt][1], acc, 0, 0, 0);
#pragma unroll
                for (int r = 0; r < 4; ++r) acc[r] = lrelu(acc[r]);
                xov[m][nt] = acc;
            }
        }
        __syncthreads();   // all A-frag reads done -> safe to clobber staging with xoT

        // C layout: col = l16 = channel, row = quad*4 + r = point -> float4 of 4 consecutive pts
        float* xoT = (float*)uLds;
#pragma unroll
        for (int m = 0; m < 4; ++m) {
            int mt = (tid >> 6) * 4 + m;
#pragma unroll
            for (int nt = 0; nt < 2; ++nt) {
                int ch = nt * 16 + l16;
                int pt = mt * 16 + quad * 4;
                *(fx4*)&xoT[ch * XOS + pt] = xov[m][nt];
            }
        }
        __syncthreads();

        // chunk-reduce: thread owns (ch = tid&31, 32-pt chunk = tid>>5); invalid pts have b=-1
        {
            int ch = tid & 31, chunk = tid >> 5;
            float acc = 0.f;
            int cur = sb[chunk * 32];
#pragma unroll
            for (int g = 0; g < 8; ++g) {
                float4 v4 = *(const float4*)&xoT[ch * XOS + chunk * 32 + g * 4];
                int4   n4 = *(const int4*)&sb[chunk * 32 + g * 4];
                float vv[4] = {v4.x, v4.y, v4.z, v4.w};
                int   nn[4] = {n4.x, n4.y, n4.z, n4.w};
#pragma unroll
                for (int k = 0; k < 4; ++k) {
                    if (nn[k] != cur) {
                        if (cur >= 0) atomicAdd(&pooled[cur * 32 + ch], acc);
                        cur = nn[k];
                        acc = vv[k];
                    } else {
                        acc += vv[k];
                    }
                }
            }
            if (cur >= 0) atomicAdd(&pooled[cur * 32 + ch], acc);
        }
        __syncthreads();   // reduce reads done -> next tile may restage
    }
}

// ---------------- Pass D: disc head per graph ----------------
__global__ __launch_bounds__(256) void k_disc(
    const float* __restrict__ pooled,
    const float* __restrict__ Wd1, const float* __restrict__ Wd2,
    float* __restrict__ out)
{
    __shared__ float sWd1T[HID * 32];  // [j][c]
    __shared__ float sWd2[HID];
    for (int k = threadIdx.x; k < 32 * HID; k += 256) sWd1T[k] = Wd1[(k % 32) * HID + k / 32];
    for (int k = threadIdx.x; k < HID; k += 256) sWd2[k] = Wd2[k];
    __syncthreads();

    int bg = blockIdx.x * 256 + threadIdx.x;
    if (bg >= NUM_GRAPHS) return;

    float p[32];
    const float4* pp = (const float4*)(pooled + (size_t)bg * 32);
#pragma unroll
    for (int c4 = 0; c4 < 8; ++c4) {
        float4 vv = pp[c4];
        p[c4 * 4 + 0] = vv.x; p[c4 * 4 + 1] = vv.y; p[c4 * 4 + 2] = vv.z; p[c4 * 4 + 3] = vv.w;
    }

    float acc = 0.f;
#pragma unroll
    for (int j = 0; j < HID; ++j) {
        const float4* wr = (const float4*)&sWd1T[j * 32];
        float s = 0.f;
#pragma unroll
        for (int c4 = 0; c4 < 8; ++c4) {
            float4 w = wr[c4];
            s += p[c4 * 4 + 0] * w.x + p[c4 * 4 + 1] * w.y + p[c4 * 4 + 2] * w.z + p[c4 * 4 + 3] * w.w;
        }
        acc += lrelu(s) * sWd2[j];
    }
    out[bg] = acc;
}

extern "C" void kernel_launch(void* const* d_in, const int* in_sizes, int n_in,
                              void* d_out, int out_size, void* d_ws, size_t ws_size,
                              hipStream_t stream) {
    const float* x     = (const float*)d_in[0];
    const int*   batch = (const int*)  d_in[1];
    const float* We1   = (const float*)d_in[2];
    const float* We2   = (const float*)d_in[3];
    const float* Wg1   = (const float*)d_in[4];
    const float* Wg2   = (const float*)d_in[5];
    const float* Wo1   = (const float*)d_in[6];
    const float* Wo2   = (const float*)d_in[7];
    const float* Wd1   = (const float*)d_in[8];
    const float* Wd2   = (const float*)d_in[9];
    float* out = (float*)d_out;

    float* x_aggr    = (float*)d_ws;
    float* pooled    = x_aggr + NUM_GRAPHS * 5;
    float* g_contrib = pooled + NUM_GRAPHS * 32;

    hipMemsetAsync(d_ws, 0, (size_t)NUM_GRAPHS * (5 + 32) * sizeof(float), stream);

    int gblk = (NUM_GRAPHS + 255) / 256;
    k_emb_aggr<<<2048, 256, 0, stream>>>(x, batch, We1, We2, x_aggr);
    k_global <<<gblk, 256, 0, stream>>>(x_aggr, Wg1, Wg2, Wo1, g_contrib);
    k_out_pool<<<1024, 256, 0, stream>>>(x, batch, We1, We2, Wo1, Wo2, g_contrib, pooled);
    k_disc   <<<gblk, 256, 0, stream>>>(pooled, Wd1, Wd2, out);
}